// Round 4
// baseline (360.690 us; speedup 1.0000x reference)
//
#include <hip/hip_runtime.h>
#include <hip/hip_bf16.h>

#define BATCH 4
#define SEQ   2048
#define EMB   1024
#define HD    64
#define BT    (BATCH * SEQ)
#define BTH   (BT * HD)
#define QROWS 4

typedef __attribute__((ext_vector_type(8))) short bf16x8;
typedef __attribute__((ext_vector_type(4))) float f32x4;

__device__ __forceinline__ float bflo(unsigned int u) { return __uint_as_float(u << 16); }

// round-to-nearest-even fp32 -> bf16 bits
__device__ __forceinline__ ushort f2bf(float f) {
    unsigned u = __float_as_uint(f);
    return (ushort)((u + 0x7FFFu + ((u >> 16) & 1u)) >> 16);
}

// ------------- input dtype detection: bf16 vs fp32 (proven: picks fp32) ----
__global__ void detect_dtype(const ushort* __restrict__ x, unsigned* __restrict__ flag)
{
    __shared__ int cnt;
    if (threadIdx.x == 0) cnt = 0;
    __syncthreads();
    int c = 0;
    for (int i = (int)threadIdx.x; i < 4096; i += 256) {
        const unsigned e = ((unsigned)x[i] >> 7) & 0xFFu;
        if (e >= 147u) ++c;
    }
    atomicAdd(&cnt, c);
    __syncthreads();
    if (threadIdx.x == 0) *flag = (cnt > 64) ? 1u : 0u;   // 1 = fp32 inputs
}

// ---------------- QKV projection: [BT,EMB] x [EMB,3*HD] via MFMA -----------
// out[t,h] = sum_e x[t,e] * W[h,e] + b[h]   (W row-major [HD,EMB] == B^T form)
// A frag: m = lane&15, k = (lane>>4)*8 + j ; B frag: n = lane&15, same k
// C/D   : col(n) = lane&15, row(m) = (lane>>4)*4 + reg
// (layout validated: round-2 MFMA vs round-3 VALU gave identical results)
__global__ __launch_bounds__(256) void qkv_proj(
    const void* __restrict__ x,
    const void* __restrict__ Wq, const void* __restrict__ bq,
    const void* __restrict__ Wk, const void* __restrict__ bk,
    const void* __restrict__ Wv, const void* __restrict__ bv,
    const unsigned* __restrict__ flag,
    float* __restrict__ qkv)
{
    const bool isf32 = (*flag != 0u);
    const int wid  = (int)((blockIdx.x * blockDim.x + threadIdx.x) >> 6);
    const int lane = (int)(threadIdx.x & 63);
    const int tile_n = wid % 12;
    const int tile_m = wid / 12;
    const int sel   = tile_n >> 2;        // 0=q, 1=k, 2=v
    const int hbase = (tile_n & 3) << 4;

    const void* W    = (sel == 0) ? Wq : ((sel == 1) ? Wk : Wv);
    const void* bias = (sel == 0) ? bq : ((sel == 1) ? bk : bv);

    const int mr   = lane & 15;
    const int quad = lane >> 4;
    const size_t aoff = (size_t)(tile_m * 16 + mr) * EMB + quad * 8;
    const size_t boff = (size_t)(hbase + mr) * EMB + quad * 8;

    f32x4 acc = {0.f, 0.f, 0.f, 0.f};
    if (!isf32) {
        const ushort* ap = (const ushort*)x + aoff;
        const ushort* bp = (const ushort*)W + boff;
        #pragma unroll 8
        for (int k0 = 0; k0 < EMB; k0 += 32) {
            bf16x8 a = *(const bf16x8*)(ap + k0);
            bf16x8 b = *(const bf16x8*)(bp + k0);
            acc = __builtin_amdgcn_mfma_f32_16x16x32_bf16(a, b, acc, 0, 0, 0);
        }
    } else {
        const float* ap = (const float*)x + aoff;
        const float* bp = (const float*)W + boff;
        #pragma unroll 4
        for (int k0 = 0; k0 < EMB; k0 += 32) {
            const float4 a0 = *(const float4*)(ap + k0);
            const float4 a1 = *(const float4*)(ap + k0 + 4);
            const float4 b0 = *(const float4*)(bp + k0);
            const float4 b1 = *(const float4*)(bp + k0 + 4);
            bf16x8 a, b;
            a[0] = (short)f2bf(a0.x); a[1] = (short)f2bf(a0.y);
            a[2] = (short)f2bf(a0.z); a[3] = (short)f2bf(a0.w);
            a[4] = (short)f2bf(a1.x); a[5] = (short)f2bf(a1.y);
            a[6] = (short)f2bf(a1.z); a[7] = (short)f2bf(a1.w);
            b[0] = (short)f2bf(b0.x); b[1] = (short)f2bf(b0.y);
            b[2] = (short)f2bf(b0.z); b[3] = (short)f2bf(b0.w);
            b[4] = (short)f2bf(b1.x); b[5] = (short)f2bf(b1.y);
            b[6] = (short)f2bf(b1.z); b[7] = (short)f2bf(b1.w);
            acc = __builtin_amdgcn_mfma_f32_16x16x32_bf16(a, b, acc, 0, 0, 0);
        }
    }

    const int h  = hbase + mr;
    const float bb = isf32 ? ((const float*)bias)[h]
                           : bflo((unsigned)((const ushort*)bias)[h]);
    float* op = qkv + (size_t)sel * BTH;
    const int t0 = tile_m * 16 + quad * 4;
    #pragma unroll
    for (int i = 0; i < 4; ++i)
        op[(size_t)(t0 + i) * HD + h] = acc[i] + bb;
}

// ---------------- causal attention, 4 query rows per block -----------------
__device__ __forceinline__ float blk_reduce(float val, bool domax, float* red, int tid)
{
    #pragma unroll
    for (int off = 32; off > 0; off >>= 1) {
        float o = __shfl_down(val, off, 64);
        val = domax ? fmaxf(val, o) : (val + o);
    }
    if ((tid & 63) == 0) red[tid >> 6] = val;
    __syncthreads();
    float r = domax ? fmaxf(fmaxf(red[0], red[1]), fmaxf(red[2], red[3]))
                    : (red[0] + red[1] + red[2] + red[3]);
    __syncthreads();
    return r;
}

__global__ __launch_bounds__(256) void attn(
    const float* __restrict__ qkv, float* __restrict__ out)
{
    const int blk  = (int)blockIdx.x;
    const int b    = blk / (SEQ / QROWS);
    const int t0   = (blk % (SEQ / QROWS)) * QROWS;
    const int tid  = (int)threadIdx.x;
    const int smax = t0 + QROWS - 1;

    const float* qb = qkv + (size_t)b * SEQ * HD;
    const float* kb = qkv + (size_t)BTH + (size_t)b * SEQ * HD;
    const float* vb = qkv + (size_t)2 * BTH + (size_t)b * SEQ * HD;

    __shared__ __align__(16) float ql[QROWS * HD];
    __shared__ __align__(16) float sl[QROWS][SEQ];   // 32 KB
    __shared__ float red[4];
    __shared__ __align__(16) float part[4][QROWS][HD];

    if (tid < QROWS * HD)
        ql[tid] = qb[(size_t)(t0 + (tid >> 6)) * HD + (tid & 63)];
    __syncthreads();

    // ---- phase 1: scores q . k ----
    float acc[8][QROWS];
    #pragma unroll
    for (int i = 0; i < 8; ++i)
        #pragma unroll
        for (int r = 0; r < QROWS; ++r) acc[i][r] = 0.f;
    const int ni = (tid <= smax) ? (((smax - tid) >> 8) + 1) : 0;

    for (int ec = 0; ec < HD; ec += 4) {
        const float4 q0 = *(const float4*)&ql[0 * HD + ec];
        const float4 q1 = *(const float4*)&ql[1 * HD + ec];
        const float4 q2 = *(const float4*)&ql[2 * HD + ec];
        const float4 q3 = *(const float4*)&ql[3 * HD + ec];
        #pragma unroll
        for (int i = 0; i < 8; ++i) {
            if (i < ni) {
                const float4 kf = *(const float4*)(kb + (size_t)(tid + (i << 8)) * HD + ec);
                acc[i][0] += q0.x*kf.x + q0.y*kf.y + q0.z*kf.z + q0.w*kf.w;
                acc[i][1] += q1.x*kf.x + q1.y*kf.y + q1.z*kf.z + q1.w*kf.w;
                acc[i][2] += q2.x*kf.x + q2.y*kf.y + q2.z*kf.z + q2.w*kf.w;
                acc[i][3] += q3.x*kf.x + q3.y*kf.y + q3.z*kf.z + q3.w*kf.w;
            }
        }
    }

    // ---- phase 2: per-row masked max ----
    float pm[QROWS] = {-INFINITY, -INFINITY, -INFINITY, -INFINITY};
    #pragma unroll
    for (int i = 0; i < 8; ++i) if (i < ni) {
        const int s = tid + (i << 8);
        #pragma unroll
        for (int r = 0; r < QROWS; ++r)
            if (s <= t0 + r) pm[r] = fmaxf(pm[r], acc[i][r] * 0.125f);
    }
    float mrow[QROWS], lrow[QROWS];
    for (int r = 0; r < QROWS; ++r) mrow[r] = blk_reduce(pm[r], true, red, tid);

    // ---- phase 3: exp + row sum; p (masked -> 0) into LDS ----
    float ps[QROWS] = {0.f, 0.f, 0.f, 0.f};
    #pragma unroll
    for (int i = 0; i < 8; ++i) if (i < ni) {
        const int s = tid + (i << 8);
        #pragma unroll
        for (int r = 0; r < QROWS; ++r) {
            const float p = (s <= t0 + r) ? __expf(acc[i][r] * 0.125f - mrow[r]) : 0.f;
            sl[r][s] = p;
            ps[r] += p;
        }
    }
    for (int r = 0; r < QROWS; ++r) lrow[r] = blk_reduce(ps[r], false, red, tid);
    // trailing __syncthreads in blk_reduce publishes sl[]

    // ---- phase 4: P @ V ----
    const int h = tid & 63, c = tid >> 6;
    float oa[QROWS] = {0.f, 0.f, 0.f, 0.f};
    const int sbeg = c * (SEQ / 4);
    const int send = (smax < sbeg + (SEQ / 4) - 1) ? smax : (sbeg + (SEQ / 4) - 1);
    int s = sbeg;
    for (; s + 3 <= send; s += 4) {
        const float4 p0 = *(const float4*)&sl[0][s];
        const float4 p1 = *(const float4*)&sl[1][s];
        const float4 p2 = *(const float4*)&sl[2][s];
        const float4 p3 = *(const float4*)&sl[3][s];
        const float v0 = vb[(size_t)(s + 0) * HD + h];
        const float v1 = vb[(size_t)(s + 1) * HD + h];
        const float v2 = vb[(size_t)(s + 2) * HD + h];
        const float v3 = vb[(size_t)(s + 3) * HD + h];
        oa[0] += p0.x*v0 + p0.y*v1 + p0.z*v2 + p0.w*v3;
        oa[1] += p1.x*v0 + p1.y*v1 + p1.z*v2 + p1.w*v3;
        oa[2] += p2.x*v0 + p2.y*v1 + p2.z*v2 + p2.w*v3;
        oa[3] += p3.x*v0 + p3.y*v1 + p3.z*v2 + p3.w*v3;
    }
    for (; s <= send; ++s) {
        const float vv = vb[(size_t)s * HD + h];
        #pragma unroll
        for (int r = 0; r < QROWS; ++r) oa[r] += sl[r][s] * vv;
    }
    #pragma unroll
    for (int r = 0; r < QROWS; ++r) part[c][r][h] = oa[r];
    __syncthreads();

    {
        const int r = tid >> 6, hh = tid & 63;
        const float sum = part[0][r][hh] + part[1][r][hh] + part[2][r][hh] + part[3][r][hh];
        out[(size_t)(b * SEQ + t0 + r) * HD + hh] = sum / lrow[r];   // fp32 output
    }
}

extern "C" void kernel_launch(void* const* d_in, const int* in_sizes, int n_in,
                              void* d_out, int out_size, void* d_ws, size_t ws_size,
                              hipStream_t stream)
{
    const void* x  = d_in[0];
    const void* Wq = d_in[1];
    const void* bq = d_in[2];
    const void* Wk = d_in[3];
    const void* bk = d_in[4];
    const void* Wv = d_in[5];
    const void* bv = d_in[6];

    unsigned* flag = (unsigned*)d_ws;
    float* qkv = (float*)((char*)d_ws + 256);        // [3][BT][HD] fp32 = 6 MB
    float* out = (float*)d_out;                      // fp32 output (reference dtype)

    detect_dtype<<<1, 256, 0, stream>>>((const ushort*)x, flag);
    qkv_proj<<<(512 * 12) / 4, 256, 0, stream>>>(x, Wq, bq, Wk, bk, Wv, bv, flag, qkv);
    attn<<<BT / QROWS, 256, 0, stream>>>(qkv, out);
}

// Round 5
// 182.949 us; speedup vs baseline: 1.9715x; 1.9715x over previous
//
#include <hip/hip_runtime.h>
#include <hip/hip_bf16.h>

#define BATCH 4
#define SEQ   2048
#define EMB   1024
#define HD    64
#define BT    (BATCH * SEQ)

// logits scale 1/sqrt(64) folded with log2(e) so softmax can use exp2 directly
#define QSCALE 0.18033688011112042f

typedef __attribute__((ext_vector_type(8))) short bf16x8;
typedef __attribute__((ext_vector_type(4))) float f32x4;

__device__ __forceinline__ ushort f2bf(float f) {   // RTN fp32 -> bf16 bits
    unsigned u = __float_as_uint(f);
    return (ushort)((u + 0x7FFFu + ((u >> 16) & 1u)) >> 16);
}

// ---------------- prep: W (fp32) -> Wb bf16 [192][1024]; biases -> fp32[192]
__global__ __launch_bounds__(256) void prep(
    const float* __restrict__ Wq, const float* __restrict__ bq,
    const float* __restrict__ Wk, const float* __restrict__ bk,
    const float* __restrict__ Wv, const float* __restrict__ bv,
    ushort* __restrict__ Wb, float* __restrict__ bb)
{
    const int r = (int)blockIdx.x;                    // 0..191
    const float* W = (r < 64) ? Wq : ((r < 128) ? Wk : Wv);
    const float* src = W + (size_t)(r & 63) * EMB;
    ushort* dst = Wb + (size_t)r * EMB;
    for (int e = (int)threadIdx.x; e < EMB; e += 256) dst[e] = f2bf(src[e]);
    if (blockIdx.x == 0 && threadIdx.x < 192) {
        const int i = (int)threadIdx.x;
        const float* B = (i < 64) ? bq : ((i < 128) ? bk : bv);
        bb[i] = B[i & 63];
    }
}

// ---------------- QKV projection: 1 wave = 16-row M-tile x all 192 outputs --
// A frag: m = lane&15, k = quad*8+j (x fp32, packed to bf16 in-register)
// B frag: n = lane&15 -> Wb row (sub*16+col), k same       (layout HW-verified R2/R3)
// C/D   : col = lane&15, row = quad*4 + reg
__global__ __launch_bounds__(64) void qkv_proj(
    const float* __restrict__ x, const ushort* __restrict__ Wb,
    const float* __restrict__ bb,
    ushort* __restrict__ qb, ushort* __restrict__ kbuf, ushort* __restrict__ vtb)
{
    const int t0   = (int)blockIdx.x * 16;
    const int lane = (int)threadIdx.x;
    const int col  = lane & 15, quad = lane >> 4;

    const float*  ap = x  + (size_t)(t0 + col) * EMB + quad * 8;
    const ushort* bp = Wb + (size_t)col * EMB + quad * 8;

    f32x4 acc[12];
    #pragma unroll
    for (int s = 0; s < 12; ++s) acc[s] = (f32x4){0.f, 0.f, 0.f, 0.f};

    for (int k0 = 0; k0 < EMB; k0 += 32) {
        const float4 a0 = *(const float4*)(ap + k0);
        const float4 a1 = *(const float4*)(ap + k0 + 4);
        bf16x8 a;
        a[0] = (short)f2bf(a0.x); a[1] = (short)f2bf(a0.y);
        a[2] = (short)f2bf(a0.z); a[3] = (short)f2bf(a0.w);
        a[4] = (short)f2bf(a1.x); a[5] = (short)f2bf(a1.y);
        a[6] = (short)f2bf(a1.z); a[7] = (short)f2bf(a1.w);
        #pragma unroll
        for (int sub = 0; sub < 12; ++sub) {
            const bf16x8 bf = *(const bf16x8*)(bp + (size_t)sub * 16 * EMB + k0);
            acc[sub] = __builtin_amdgcn_mfma_f32_16x16x32_bf16(a, bf, acc[sub], 0, 0, 0);
        }
    }

    const int b     = t0 >> 11;                       // batch
    const int sloc0 = (t0 & (SEQ - 1)) + quad * 4;    // local s of row group
    #pragma unroll
    for (int sub = 0; sub < 12; ++sub) {
        const int hrow = sub * 16 + col;              // 0..191
        const float bias = bb[hrow];
        const int sel = hrow >> 6, h = hrow & 63;
        if (sel == 0) {
            #pragma unroll
            for (int i = 0; i < 4; ++i)
                qb[(size_t)(t0 + quad * 4 + i) * HD + h] = f2bf((acc[sub][i] + bias) * QSCALE);
        } else if (sel == 1) {
            #pragma unroll
            for (int i = 0; i < 4; ++i)
                kbuf[(size_t)(t0 + quad * 4 + i) * HD + h] = f2bf(acc[sub][i] + bias);
        } else {                                      // v, transposed [64][SEQ]
            ushort4 pk;
            pk.x = f2bf(acc[sub][0] + bias); pk.y = f2bf(acc[sub][1] + bias);
            pk.z = f2bf(acc[sub][2] + bias); pk.w = f2bf(acc[sub][3] + bias);
            *(ushort4*)(vtb + ((size_t)(b * 64 + h)) * SEQ + sloc0) = pk;
        }
    }
}

// ---------------- flash attention: 1 wave = 16 query rows, MFMA everywhere --
__global__ __launch_bounds__(64) void attn_mfma(
    const ushort* __restrict__ qb, const ushort* __restrict__ kbuf,
    const ushort* __restrict__ vtb, float* __restrict__ out)
{
    const int b    = (int)blockIdx.x & 3;
    const int tile = 127 - ((int)blockIdx.x >> 2);    // longest tiles dispatch first
    const int t0   = tile * 16;
    const int lane = (int)threadIdx.x;
    const int col  = lane & 15, quad = lane >> 4;

    const ushort* q  = qb   + ((size_t)b * SEQ + t0) * HD;
    const ushort* kb = kbuf + (size_t)b * SEQ * HD;
    const ushort* vb = vtb  + (size_t)b * HD * SEQ;

    const bf16x8 aq0 = *(const bf16x8*)(q + col * HD + quad * 8);
    const bf16x8 aq1 = *(const bf16x8*)(q + col * HD + 32 + quad * 8);

    float m_r[4], l_r[4];
    f32x4 o[4];
    #pragma unroll
    for (int i = 0; i < 4; ++i) { m_r[i] = -1e30f; l_r[i] = 0.f; o[i] = (f32x4){0.f,0.f,0.f,0.f}; }

    __shared__ ushort pt[16][72];                     // stride 72: 16B-aligned rows

    const int ntiles = (tile >> 2) + 1;               // K-tiles of 64 covering s<=t0+15
    for (int it = 0; it < ntiles; ++it) {
        const int s0 = it * 64;

        // ---- scores S = (q*scale) . k^T, C/D layout: row=quad*4+reg, col(s)=sub*16+col
        f32x4 sc[4];
        #pragma unroll
        for (int sub = 0; sub < 4; ++sub) {
            const ushort* kr = kb + (size_t)(s0 + sub * 16 + col) * HD;
            const bf16x8 k0 = *(const bf16x8*)(kr + quad * 8);
            const bf16x8 k1 = *(const bf16x8*)(kr + 32 + quad * 8);
            f32x4 z = {0.f, 0.f, 0.f, 0.f};
            z = __builtin_amdgcn_mfma_f32_16x16x32_bf16(aq0, k0, z, 0, 0, 0);
            z = __builtin_amdgcn_mfma_f32_16x16x32_bf16(aq1, k1, z, 0, 0, 0);
            sc[sub] = z;
        }

        if (it == ntiles - 1) {                       // only the last tile crosses diag
            #pragma unroll
            for (int sub = 0; sub < 4; ++sub)
                #pragma unroll
                for (int i = 0; i < 4; ++i) {
                    const int s = s0 + sub * 16 + col, t = t0 + quad * 4 + i;
                    if (s > t) sc[sub][i] = -1e30f;
                }
        }

        // ---- online softmax (rows live in (quad,reg); butterfly over 16 lanes/quad)
        float mx[4], alpha[4], ps[4];
        #pragma unroll
        for (int i = 0; i < 4; ++i)
            mx[i] = fmaxf(fmaxf(sc[0][i], sc[1][i]), fmaxf(sc[2][i], sc[3][i]));
        #pragma unroll
        for (int d = 1; d < 16; d <<= 1)
            #pragma unroll
            for (int i = 0; i < 4; ++i) mx[i] = fmaxf(mx[i], __shfl_xor(mx[i], d, 64));
        #pragma unroll
        for (int i = 0; i < 4; ++i) {
            const float nm = fmaxf(m_r[i], mx[i]);
            alpha[i] = exp2f(m_r[i] - nm);
            m_r[i] = nm;
            ps[i] = 0.f;
        }
        #pragma unroll
        for (int sub = 0; sub < 4; ++sub)
            #pragma unroll
            for (int i = 0; i < 4; ++i) {
                const float p = exp2f(sc[sub][i] - m_r[i]);
                ps[i] += p;
                pt[quad * 4 + i][sub * 16 + col] = f2bf(p);
            }
        #pragma unroll
        for (int d = 1; d < 16; d <<= 1)
            #pragma unroll
            for (int i = 0; i < 4; ++i) ps[i] += __shfl_xor(ps[i], d, 64);
        #pragma unroll
        for (int i = 0; i < 4; ++i) l_r[i] = l_r[i] * alpha[i] + ps[i];
        #pragma unroll
        for (int sub = 0; sub < 4; ++sub)
            #pragma unroll
            for (int i = 0; i < 4; ++i) o[sub][i] *= alpha[i];

        // ---- P: C/D layout -> A-operand layout via wave-private LDS round trip
        __asm__ volatile("s_waitcnt lgkmcnt(0)" ::: "memory");
        const bf16x8 ap0 = *(const bf16x8*)&pt[col][quad * 8];
        const bf16x8 ap1 = *(const bf16x8*)&pt[col][32 + quad * 8];

        // ---- O += P @ V  (B-frag rows = v^T[h][s], contiguous over s)
        #pragma unroll
        for (int sub = 0; sub < 4; ++sub) {
            const ushort* vr = vb + (size_t)(sub * 16 + col) * SEQ + s0;
            const bf16x8 v0 = *(const bf16x8*)(vr + quad * 8);
            const bf16x8 v1 = *(const bf16x8*)(vr + 32 + quad * 8);
            o[sub] = __builtin_amdgcn_mfma_f32_16x16x32_bf16(ap0, v0, o[sub], 0, 0, 0);
            o[sub] = __builtin_amdgcn_mfma_f32_16x16x32_bf16(ap1, v1, o[sub], 0, 0, 0);
        }
    }

    // ---- epilogue: normalize, fp32 store
    float* ob = out + ((size_t)b * SEQ + t0) * HD;
    float rl[4];
    #pragma unroll
    for (int i = 0; i < 4; ++i) rl[i] = 1.0f / l_r[i];
    #pragma unroll
    for (int sub = 0; sub < 4; ++sub)
        #pragma unroll
        for (int i = 0; i < 4; ++i)
            ob[(size_t)(quad * 4 + i) * HD + sub * 16 + col] = o[sub][i] * rl[i];
}

extern "C" void kernel_launch(void* const* d_in, const int* in_sizes, int n_in,
                              void* d_out, int out_size, void* d_ws, size_t ws_size,
                              hipStream_t stream)
{
    const float* x  = (const float*)d_in[0];
    const float* Wq = (const float*)d_in[1];
    const float* bq = (const float*)d_in[2];
    const float* Wk = (const float*)d_in[3];
    const float* bk = (const float*)d_in[4];
    const float* Wv = (const float*)d_in[5];
    const float* bv = (const float*)d_in[6];
    float* out = (float*)d_out;

    char* ws = (char*)d_ws;
    ushort* Wb   = (ushort*)(ws);                       // 384 KB
    float*  bb   = (float*)(ws + 0x60000);              // 768 B
    ushort* qb   = (ushort*)(ws + 0x61000);             // 1 MB
    ushort* kbuf = (ushort*)(ws + 0x61000 + 0x100000);  // 1 MB
    ushort* vtb  = (ushort*)(ws + 0x61000 + 0x200000);  // 1 MB

    prep<<<192, 256, 0, stream>>>(Wq, bq, Wk, bk, Wv, bv, Wb, bb);
    qkv_proj<<<BT / 16, 64, 0, stream>>>(x, Wb, bb, qb, kbuf, vtb);
    attn_mfma<<<BT / 16, 64, 0, stream>>>(qb, kbuf, vtb, out);
}

// Round 6
// 139.680 us; speedup vs baseline: 2.5823x; 1.3098x over previous
//
#include <hip/hip_runtime.h>
#include <hip/hip_bf16.h>

#define BATCH 4
#define SEQ   2048
#define EMB   1024
#define HD    64
#define BT    (BATCH * SEQ)

// logits scale 1/sqrt(64) folded with log2(e) so softmax can use exp2 directly
#define QSCALE 0.18033688011112042f

typedef __attribute__((ext_vector_type(8))) short bf16x8;
typedef __attribute__((ext_vector_type(4))) float f32x4;

__device__ __forceinline__ ushort f2bf(float f) {   // RTN fp32 -> bf16 bits
    unsigned u = __float_as_uint(f);
    return (ushort)((u + 0x7FFFu + ((u >> 16) & 1u)) >> 16);
}

// ---------------- prep: W (fp32) -> Wb bf16 [192][1024]; biases -> fp32[192]
__global__ __launch_bounds__(256) void prep(
    const float* __restrict__ Wq, const float* __restrict__ bq,
    const float* __restrict__ Wk, const float* __restrict__ bk,
    const float* __restrict__ Wv, const float* __restrict__ bv,
    ushort* __restrict__ Wb, float* __restrict__ bb)
{
    const int r = (int)blockIdx.x;                    // 0..191
    const float* W = (r < 64) ? Wq : ((r < 128) ? Wk : Wv);
    const float* src = W + (size_t)(r & 63) * EMB;
    ushort* dst = Wb + (size_t)r * EMB;
    for (int e = (int)threadIdx.x; e < EMB; e += 256) dst[e] = f2bf(src[e]);
    if (blockIdx.x == 0 && threadIdx.x < 192) {
        const int i = (int)threadIdx.x;
        const float* B = (i < 64) ? bq : ((i < 128) ? bk : bv);
        bb[i] = B[i & 63];
    }
}

// ---------------- QKV projection: block = 16-row M-tile, 4 waves split EMB --
// wave wv reduces k in [wv*256, wv*256+256); partials combined through LDS.
// A frag: m = lane&15, k = quad*8+j ; B frag: n = lane&15 (Wb row sub*16+col)
// C/D   : col = lane&15, row = quad*4 + reg        (layout HW-verified R2/R3)
__global__ __launch_bounds__(256) void qkv_proj(
    const float* __restrict__ x, const ushort* __restrict__ Wb,
    const float* __restrict__ bb,
    ushort* __restrict__ qb, ushort* __restrict__ kbuf, ushort* __restrict__ vtb)
{
    const int t0   = (int)blockIdx.x * 16;
    const int tid  = (int)threadIdx.x;
    const int wv   = tid >> 6;
    const int lane = tid & 63;
    const int col  = lane & 15, quad = lane >> 4;

    const float*  ap = x  + (size_t)(t0 + col) * EMB + wv * 256 + quad * 8;
    const ushort* bp = Wb + (size_t)col * EMB + wv * 256 + quad * 8;

    f32x4 acc[12];
    #pragma unroll
    for (int s = 0; s < 12; ++s) acc[s] = (f32x4){0.f, 0.f, 0.f, 0.f};

    #pragma unroll 2
    for (int k0 = 0; k0 < 256; k0 += 32) {
        const float4 a0 = *(const float4*)(ap + k0);
        const float4 a1 = *(const float4*)(ap + k0 + 4);
        bf16x8 a;
        a[0] = (short)f2bf(a0.x); a[1] = (short)f2bf(a0.y);
        a[2] = (short)f2bf(a0.z); a[3] = (short)f2bf(a0.w);
        a[4] = (short)f2bf(a1.x); a[5] = (short)f2bf(a1.y);
        a[6] = (short)f2bf(a1.z); a[7] = (short)f2bf(a1.w);
        #pragma unroll
        for (int sub = 0; sub < 12; ++sub) {
            const bf16x8 bf = *(const bf16x8*)(bp + (size_t)sub * 16 * EMB + k0);
            acc[sub] = __builtin_amdgcn_mfma_f32_16x16x32_bf16(a, bf, acc[sub], 0, 0, 0);
        }
    }

    __shared__ float red[4][12][16][17];              // +1 pad: 2-way banks max
    #pragma unroll
    for (int sub = 0; sub < 12; ++sub)
        #pragma unroll
        for (int i = 0; i < 4; ++i)
            red[wv][sub][quad * 4 + i][col] = acc[sub][i];
    __syncthreads();

    const int row = tid >> 4, c = tid & 15;
    const int b = t0 >> 11;
    const int sloc = (t0 & (SEQ - 1)) + row;
    #pragma unroll
    for (int sub = 0; sub < 12; ++sub) {
        const float s = red[0][sub][row][c] + red[1][sub][row][c]
                      + red[2][sub][row][c] + red[3][sub][row][c] + bb[sub * 16 + c];
        if (sub < 4)
            qb[(size_t)(t0 + row) * HD + sub * 16 + c] = f2bf(s * QSCALE);
        else if (sub < 8)
            kbuf[(size_t)(t0 + row) * HD + (sub - 4) * 16 + c] = f2bf(s);
        else
            vtb[((size_t)(b * 64 + (sub - 8) * 16 + c)) * SEQ + sloc] = f2bf(s);
    }
}

// ---------------- flash attention: block = 16 q-rows, 4 waves split keys ----
__global__ __launch_bounds__(256) void attn_mfma(
    const ushort* __restrict__ qb, const ushort* __restrict__ kbuf,
    const ushort* __restrict__ vtb, float* __restrict__ out)
{
    const int b    = (int)blockIdx.x & 3;
    const int tile = 127 - ((int)blockIdx.x >> 2);    // longest tiles dispatch first
    const int t0   = tile * 16;
    const int tid  = (int)threadIdx.x;
    const int wv   = tid >> 6;
    const int lane = tid & 63;
    const int col  = lane & 15, quad = lane >> 4;

    const ushort* q  = qb   + ((size_t)b * SEQ + t0) * HD;
    const ushort* kb = kbuf + (size_t)b * SEQ * HD;
    const ushort* vb = vtb  + (size_t)b * HD * SEQ;

    const bf16x8 aq0 = *(const bf16x8*)(q + col * HD + quad * 8);
    const bf16x8 aq1 = *(const bf16x8*)(q + col * HD + 32 + quad * 8);

    float m_r[4], l_r[4];
    f32x4 o[4];
    #pragma unroll
    for (int i = 0; i < 4; ++i) { m_r[i] = -1e30f; l_r[i] = 0.f; o[i] = (f32x4){0.f,0.f,0.f,0.f}; }

    __shared__ ushort pt[4][16][72];                  // per-wave P transpose tile
    __shared__ __align__(16) float op[4][16][68];     // partial O (stride 68: 16B rows)
    __shared__ float ml[4][16], ll[4][16];

    const int ntiles = (tile >> 2) + 1;               // K-tiles of 64 covering s<=t0+15
    for (int it = wv; it < ntiles; it += 4) {
        const int s0 = it * 64;

        // ---- S = (q*scale) . k^T ; C/D: row=quad*4+reg, col(s)=sub*16+col
        f32x4 sc[4];
        #pragma unroll
        for (int sub = 0; sub < 4; ++sub) {
            const ushort* kr = kb + (size_t)(s0 + sub * 16 + col) * HD;
            const bf16x8 k0 = *(const bf16x8*)(kr + quad * 8);
            const bf16x8 k1 = *(const bf16x8*)(kr + 32 + quad * 8);
            f32x4 z = {0.f, 0.f, 0.f, 0.f};
            z = __builtin_amdgcn_mfma_f32_16x16x32_bf16(aq0, k0, z, 0, 0, 0);
            z = __builtin_amdgcn_mfma_f32_16x16x32_bf16(aq1, k1, z, 0, 0, 0);
            sc[sub] = z;
        }

        if (it == ntiles - 1) {                       // only the diagonal tile masks
            #pragma unroll
            for (int sub = 0; sub < 4; ++sub)
                #pragma unroll
                for (int i = 0; i < 4; ++i) {
                    const int s = s0 + sub * 16 + col, t = t0 + quad * 4 + i;
                    if (s > t) sc[sub][i] = -1e30f;
                }
        }

        // ---- online softmax (rows in (quad,reg); butterfly over 16 lanes/quad)
        float mx[4], alpha[4], ps[4];
        #pragma unroll
        for (int i = 0; i < 4; ++i)
            mx[i] = fmaxf(fmaxf(sc[0][i], sc[1][i]), fmaxf(sc[2][i], sc[3][i]));
        #pragma unroll
        for (int d = 1; d < 16; d <<= 1)
            #pragma unroll
            for (int i = 0; i < 4; ++i) mx[i] = fmaxf(mx[i], __shfl_xor(mx[i], d, 64));
        #pragma unroll
        for (int i = 0; i < 4; ++i) {
            const float nm = fmaxf(m_r[i], mx[i]);
            alpha[i] = exp2f(m_r[i] - nm);
            m_r[i] = nm;
            ps[i] = 0.f;
        }
        #pragma unroll
        for (int sub = 0; sub < 4; ++sub)
            #pragma unroll
            for (int i = 0; i < 4; ++i) {
                const float p = exp2f(sc[sub][i] - m_r[i]);
                ps[i] += p;
                pt[wv][quad * 4 + i][sub * 16 + col] = f2bf(p);
            }
        #pragma unroll
        for (int d = 1; d < 16; d <<= 1)
            #pragma unroll
            for (int i = 0; i < 4; ++i) ps[i] += __shfl_xor(ps[i], d, 64);
        #pragma unroll
        for (int i = 0; i < 4; ++i) l_r[i] = l_r[i] * alpha[i] + ps[i];
        #pragma unroll
        for (int sub = 0; sub < 4; ++sub)
            #pragma unroll
            for (int i = 0; i < 4; ++i) o[sub][i] *= alpha[i];

        // ---- P: C/D -> A-operand via wave-private LDS (wave-internal wait only)
        __asm__ volatile("s_waitcnt lgkmcnt(0)" ::: "memory");
        const bf16x8 ap0 = *(const bf16x8*)&pt[wv][col][quad * 8];
        const bf16x8 ap1 = *(const bf16x8*)&pt[wv][col][32 + quad * 8];

        // ---- O += P @ V  (B-frag rows = v^T[h][s], contiguous over s)
        #pragma unroll
        for (int sub = 0; sub < 4; ++sub) {
            const ushort* vr = vb + (size_t)(sub * 16 + col) * SEQ + s0;
            const bf16x8 v0 = *(const bf16x8*)(vr + quad * 8);
            const bf16x8 v1 = *(const bf16x8*)(vr + 32 + quad * 8);
            o[sub] = __builtin_amdgcn_mfma_f32_16x16x32_bf16(ap0, v0, o[sub], 0, 0, 0);
            o[sub] = __builtin_amdgcn_mfma_f32_16x16x32_bf16(ap1, v1, o[sub], 0, 0, 0);
        }
    }

    // ---- publish per-wave partial state
    #pragma unroll
    for (int sub = 0; sub < 4; ++sub)
        #pragma unroll
        for (int i = 0; i < 4; ++i)
            op[wv][quad * 4 + i][sub * 16 + col] = o[sub][i];
    if (col == 0) {
        #pragma unroll
        for (int i = 0; i < 4; ++i) {
            ml[wv][quad * 4 + i] = m_r[i];
            ll[wv][quad * 4 + i] = l_r[i];
        }
    }
    __syncthreads();

    // ---- merge 4 partials: thread = (row, 4-col group)
    const int row = tid >> 4, c0 = (tid & 15) * 4;
    const float m0 = ml[0][row], m1 = ml[1][row], m2 = ml[2][row], m3 = ml[3][row];
    const float ms = fmaxf(fmaxf(m0, m1), fmaxf(m2, m3));
    const float w0 = exp2f(m0 - ms), w1 = exp2f(m1 - ms);
    const float w2 = exp2f(m2 - ms), w3 = exp2f(m3 - ms);
    const float ls = w0 * ll[0][row] + w1 * ll[1][row] + w2 * ll[2][row] + w3 * ll[3][row];
    const float4 p0 = *(const float4*)&op[0][row][c0];
    const float4 p1 = *(const float4*)&op[1][row][c0];
    const float4 p2 = *(const float4*)&op[2][row][c0];
    const float4 p3 = *(const float4*)&op[3][row][c0];
    const float rinv = 1.0f / ls;
    float4 r;
    r.x = (w0 * p0.x + w1 * p1.x + w2 * p2.x + w3 * p3.x) * rinv;
    r.y = (w0 * p0.y + w1 * p1.y + w2 * p2.y + w3 * p3.y) * rinv;
    r.z = (w0 * p0.z + w1 * p1.z + w2 * p2.z + w3 * p3.z) * rinv;
    r.w = (w0 * p0.w + w1 * p1.w + w2 * p2.w + w3 * p3.w) * rinv;
    *(float4*)(out + ((size_t)b * SEQ + t0 + row) * HD + c0) = r;
}

extern "C" void kernel_launch(void* const* d_in, const int* in_sizes, int n_in,
                              void* d_out, int out_size, void* d_ws, size_t ws_size,
                              hipStream_t stream)
{
    const float* x  = (const float*)d_in[0];
    const float* Wq = (const float*)d_in[1];
    const float* bq = (const float*)d_in[2];
    const float* Wk = (const float*)d_in[3];
    const float* bk = (const float*)d_in[4];
    const float* Wv = (const float*)d_in[5];
    const float* bv = (const float*)d_in[6];
    float* out = (float*)d_out;

    char* ws = (char*)d_ws;
    ushort* Wb   = (ushort*)(ws);                       // 384 KB
    float*  bb   = (float*)(ws + 0x60000);              // 768 B
    ushort* qb   = (ushort*)(ws + 0x61000);             // 1 MB
    ushort* kbuf = (ushort*)(ws + 0x61000 + 0x100000);  // 1 MB
    ushort* vtb  = (ushort*)(ws + 0x61000 + 0x200000);  // 1 MB

    prep<<<192, 256, 0, stream>>>(Wq, bq, Wk, bk, Wv, bv, Wb, bb);
    qkv_proj<<<BT / 16, 256, 0, stream>>>(x, Wb, bb, qb, kbuf, vtb);
    attn_mfma<<<BT / 16, 256, 0, stream>>>(qb, kbuf, vtb, out);
}